// Round 5
// baseline (211.857 us; speedup 1.0000x reference)
//
#include <hip/hip_runtime.h>
#include <hip/hip_bf16.h>

// GegenbauerKAN layer == fused BF16-MFMA GEMM, M=16384 N=512 K=4096 (i*8+d).
// ALPHA=1 => Chebyshev-U recurrence: C_{n+1} = 2t*C_n - C_{n-1}, t = tanh(x).
// R2: coeffs pre-converted to bf16 in d_ws (cvt_w), 16B global_load_lds.
// R3 (REVERTED): explicit dbuf pipeline -6%.
// R4: 4 blocks/CU + v_cvt_pk_bf16_f32 (100us). R5: K-split waves (94us).
// R6: BN=256, VALU halved but occupancy halved -> flat (95us).
//     Accounting: LDS pipe ~55-60us/CU is the dominant consumer (MFMA 33,
//     VALU 19). R5/R6 results both consistent with LDS-bound.
// R7: ELIMINATE LDS AND BARRIERS ENTIRELY.
//     - A-frag of lane(fm,fq) == 8 features of ONE x value -> compute in
//       registers (1 gather + tanh + recurrence + 4 cvt_pk). M-stacked waves
//       => zero intra-wave redundancy; device redundancy 4x (N-panels) but
//       VALU est. only ~12us/CU.
//     - B-frag == 8 contiguous bf16 in wbf -> direct global_load_dwordx4
//       (256B/fq-group coalesced), L2-resident (W=4MB), tm=4 reuse =>
//       0.25KB/MFMA ~ 28us/CU of L2 pipe.
//     Wave tile 64x128 (tm=4,tn=8), block = 4 M-stacked waves (256x128),
//     grid (M/256=64, N/128=4): consecutive blocks share the same W panel.

#define I_DIM 512
#define O_DIM 512
#define NDEG 8
#define KITERS 64              // 64 iters x 8 i-values
#define W_ELEMS (I_DIM * O_DIM * NDEG)   // 2,097,152

typedef __attribute__((ext_vector_type(8))) short s8v;    // MFMA A/B frag (8 bf16)
typedef __attribute__((ext_vector_type(4))) float f32x4;  // MFMA C/D frag
typedef unsigned short u16;

// HW packed f32->bf16 (RNE): D[15:0]=bf16(lo), D[31:16]=bf16(hi). 1 VALU op.
__device__ __forceinline__ unsigned cvt_pk_bf16(float lo, float hi) {
    unsigned r;
    asm("v_cvt_pk_bf16_f32 %0, %1, %2" : "=v"(r) : "v"(lo), "v"(hi));
    return r;
}

__device__ __forceinline__ float fast_tanh(float v) {
    float e = __expf(v + v);
    float r = __builtin_amdgcn_rcpf(e + 1.0f);
    return 1.0f - (r + r);
}

// Build the A-fragment (8 Chebyshev-U features of one x value) in registers.
__device__ __forceinline__ s8v feat_frag(float xv) {
    const float t  = fast_tanh(xv);
    const float t2 = t + t;
    const float c1 = t2;
    const float c2 = t2 * c1 - 1.0f;
    const float c3 = t2 * c2 - c1;
    const float c4 = t2 * c3 - c2;
    const float c5 = t2 * c4 - c3;
    const float c6 = t2 * c5 - c4;
    const float c7 = t2 * c6 - c5;
    union { s8v s; unsigned u[4]; } pk;
    pk.u[0] = cvt_pk_bf16(1.0f, c1);
    pk.u[1] = cvt_pk_bf16(c2, c3);
    pk.u[2] = cvt_pk_bf16(c4, c5);
    pk.u[3] = cvt_pk_bf16(c6, c7);
    return pk.s;
}

// ---- one-shot coeffs fp32 -> bf16 into workspace (re-run every call; ws is re-poisoned)
extern "C" __global__ __launch_bounds__(256)
void cvt_w(const float* __restrict__ cf, u16* __restrict__ wbf) {
    const size_t idx = ((size_t)blockIdx.x * 256 + threadIdx.x) * 4;
    const float4 v = *reinterpret_cast<const float4*>(cf + idx);
    unsigned* dst = reinterpret_cast<unsigned*>(wbf + idx);
    dst[0] = cvt_pk_bf16(v.x, v.y);
    dst[1] = cvt_pk_bf16(v.z, v.w);
}

template <bool PRECONV>
__global__ __launch_bounds__(256, 2)
void gegen_gemm(const float* __restrict__ x,
                const float* __restrict__ cf,
                const u16* __restrict__ wbf,
                float* __restrict__ out)
{
    const int tid  = threadIdx.x;
    const int lane = tid & 63;
    const int wave = tid >> 6;             // 0..3, M-stacked (wave owns 64 rows)
    const int fm   = lane & 15;
    const int fq   = lane >> 4;

    const int bm0 = blockIdx.x * 256 + wave * 64;   // wave's M base
    const int bn0 = blockIdx.y * 128;               // wave's N base (whole block)

    // per-lane x row pointers, tm = 0..3 (rows bm0 + tm*16 + fm)
    const float* xr0 = x + (size_t)(bm0 +  0 + fm) * I_DIM;
    const float* xr1 = x + (size_t)(bm0 + 16 + fm) * I_DIM;
    const float* xr2 = x + (size_t)(bm0 + 32 + fm) * I_DIM;
    const float* xr3 = x + (size_t)(bm0 + 48 + fm) * I_DIM;

    f32x4 acc[4][8];
#pragma unroll
    for (int a = 0; a < 4; ++a)
#pragma unroll
        for (int b = 0; b < 8; ++b)
            acc[a][b] = (f32x4){0.0f, 0.0f, 0.0f, 0.0f};

    for (int it = 0; it < KITERS; ++it) {
#pragma unroll
        for (int kc = 0; kc < 2; ++kc) {
            const int i0 = it * 8 + kc * 4 + fq;    // this lane's i index

            // ---- B frags: direct from global (L2-resident W), 16B each ----
            s8v bfr[8];
            if (PRECONV) {
                const u16* wb = wbf + ((size_t)i0 * O_DIM + bn0 + fm) * NDEG;
#pragma unroll
                for (int tn = 0; tn < 8; ++tn)
                    bfr[tn] = *reinterpret_cast<const s8v*>(wb + (size_t)tn * 16 * NDEG);
            } else {
                const float* wb = cf + ((size_t)i0 * O_DIM + bn0 + fm) * NDEG;
#pragma unroll
                for (int tn = 0; tn < 8; ++tn) {
                    const float4 w0 = reinterpret_cast<const float4*>(wb + (size_t)tn * 16 * NDEG)[0];
                    const float4 w1 = reinterpret_cast<const float4*>(wb + (size_t)tn * 16 * NDEG)[1];
                    union { s8v s; unsigned u[4]; } pk;
                    pk.u[0] = cvt_pk_bf16(w0.x, w0.y);
                    pk.u[1] = cvt_pk_bf16(w0.z, w0.w);
                    pk.u[2] = cvt_pk_bf16(w1.x, w1.y);
                    pk.u[3] = cvt_pk_bf16(w1.z, w1.w);
                    bfr[tn] = pk.s;
                }
            }

            // ---- A frags: gather 4 x values, features in registers ----
            // (VALU chain ~200cy naturally covers the B-load L2 latency)
            const float x0 = xr0[i0];
            const float x1 = xr1[i0];
            const float x2 = xr2[i0];
            const float x3 = xr3[i0];
            s8v afr[4];
            afr[0] = feat_frag(x0);
            afr[1] = feat_frag(x1);
            afr[2] = feat_frag(x2);
            afr[3] = feat_frag(x3);

            // ---- 32 MFMAs ----
#pragma unroll
            for (int tm = 0; tm < 4; ++tm)
#pragma unroll
                for (int tn = 0; tn < 8; ++tn)
                    acc[tm][tn] = __builtin_amdgcn_mfma_f32_16x16x32_bf16(
                        afr[tm], bfr[tn], acc[tm][tn], 0, 0, 0);
        }
    }

    // ---- epilogue: C/D col=lane&15, row=fq*4+reg ----
#pragma unroll
    for (int tm = 0; tm < 4; ++tm) {
#pragma unroll
        for (int tn = 0; tn < 8; ++tn) {
            const int row = bm0 + tm * 16 + fq * 4;
            const int col = bn0 + tn * 16 + fm;
#pragma unroll
            for (int r = 0; r < 4; ++r)
                out[(size_t)(row + r) * O_DIM + col] = acc[tm][tn][r];
        }
    }
}

extern "C" void kernel_launch(void* const* d_in, const int* in_sizes, int n_in,
                              void* d_out, int out_size, void* d_ws, size_t ws_size,
                              hipStream_t stream) {
    const float* x  = (const float*)d_in[0];
    const float* cf = (const float*)d_in[1];
    float* out = (float*)d_out;
    const int M = in_sizes[0] / I_DIM;            // 16384
    dim3 grid(M / 256, O_DIM / 128);              // (64, 4): consecutive blocks share W panel
    dim3 block(256, 1, 1);

    if (ws_size >= (size_t)W_ELEMS * sizeof(u16)) {
        u16* wbf = (u16*)d_ws;
        cvt_w<<<W_ELEMS / 1024, 256, 0, stream>>>(cf, wbf);
        gegen_gemm<true><<<grid, block, 0, stream>>>(x, cf, wbf, out);
    } else {
        gegen_gemm<false><<<grid, block, 0, stream>>>(x, cf, nullptr, out);
    }
}

// Round 6
// 152.956 us; speedup vs baseline: 1.3851x; 1.3851x over previous
//
#include <hip/hip_runtime.h>
#include <hip/hip_bf16.h>

// GegenbauerKAN layer == fused BF16-MFMA GEMM, M=16384 N=512 K=4096 (i*8+d).
// ALPHA=1 => Chebyshev-U recurrence: C_{n+1} = 2t*C_n - C_{n-1}, t = tanh(x).
// R2: coeffs pre-converted to bf16 in d_ws (cvt_w).
// R3 (REVERTED): explicit dbuf -6%. R4: 4 blk/CU + cvt_pk (100us).
// R5: K-split waves (94us). R6: BN=256 VALU halved, occupancy halved, flat.
// R7 (REVERTED): no-LDS reg-direct, but grid=256 blocks = 1 wave/SIMD ->
//     latency-bound, 144us. Pipes were fine (FETCH 33MB: L3 absorbs all).
// R8: R7 structure + TLP restored:
//     - block = 4 waves = (2 M-slices) x (2 K-halves); grid (128,4)=512
//       blocks = 2 blocks/CU = 2 waves/SIMD. K-partials reduced via LDS
//       epilogue (R5-proven pattern).
//     - x: per-lane 32B row load (2 dwordx4) -> private LDS slot ->
//       wave-synchronous lgkmcnt(0) (NO __syncthreads in main loop) ->
//       8 scalar reads back; features computed in registers (A-frag of
//       lane(fm,fq) = 8 Chebyshev features of ONE x value).
//     - B-frags direct global dwordx4 from L2-resident wbf (16 contiguous
//       bf16 = one frag), issued at iter top; feature VALU hides latency.

#define I_DIM 512
#define O_DIM 512
#define NDEG 8
#define KH_ITERS 32            // 32 i-octets per K-half wave
#define W_ELEMS (I_DIM * O_DIM * NDEG)   // 2,097,152

typedef __attribute__((ext_vector_type(8))) short s8v;    // MFMA A/B frag (8 bf16)
typedef __attribute__((ext_vector_type(4))) float f32x4;  // MFMA C/D frag
typedef unsigned short u16;

// HW packed f32->bf16 (RNE): D[15:0]=bf16(lo), D[31:16]=bf16(hi). 1 VALU op.
__device__ __forceinline__ unsigned cvt_pk_bf16(float lo, float hi) {
    unsigned r;
    asm("v_cvt_pk_bf16_f32 %0, %1, %2" : "=v"(r) : "v"(lo), "v"(hi));
    return r;
}

__device__ __forceinline__ float fast_tanh(float v) {
    float e = __expf(v + v);
    float r = __builtin_amdgcn_rcpf(e + 1.0f);
    return 1.0f - (r + r);
}

// Build the A-fragment (8 Chebyshev-U features of one x value) in registers.
__device__ __forceinline__ s8v feat_frag(float xv) {
    const float t  = fast_tanh(xv);
    const float t2 = t + t;
    const float c1 = t2;
    const float c2 = t2 * c1 - 1.0f;
    const float c3 = t2 * c2 - c1;
    const float c4 = t2 * c3 - c2;
    const float c5 = t2 * c4 - c3;
    const float c6 = t2 * c5 - c4;
    const float c7 = t2 * c6 - c5;
    union { s8v s; unsigned u[4]; } pk;
    pk.u[0] = cvt_pk_bf16(1.0f, c1);
    pk.u[1] = cvt_pk_bf16(c2, c3);
    pk.u[2] = cvt_pk_bf16(c4, c5);
    pk.u[3] = cvt_pk_bf16(c6, c7);
    return pk.s;
}

// ---- one-shot coeffs fp32 -> bf16 into workspace (re-run every call; ws is re-poisoned)
extern "C" __global__ __launch_bounds__(256)
void cvt_w(const float* __restrict__ cf, u16* __restrict__ wbf) {
    const size_t idx = ((size_t)blockIdx.x * 256 + threadIdx.x) * 4;
    const float4 v = *reinterpret_cast<const float4*>(cf + idx);
    unsigned* dst = reinterpret_cast<unsigned*>(wbf + idx);
    dst[0] = cvt_pk_bf16(v.x, v.y);
    dst[1] = cvt_pk_bf16(v.z, v.w);
}

template <bool PRECONV>
__global__ __launch_bounds__(256, 2)
void gegen_gemm(const float* __restrict__ x,
                const float* __restrict__ cf,
                const u16* __restrict__ wbf,
                float* __restrict__ out)
{
    // 16KB union: main loop = per-wave x slots [wave][buf][64][8];
    //             epilogue = reduce buffer [m4][16][128].
    __shared__ float smem[4096];

    const int tid  = threadIdx.x;
    const int lane = tid & 63;
    const int wave = tid >> 6;             // 0..3
    const int m4   = wave & 1;             // M-slice (64 rows)
    const int kh   = wave >> 1;            // K-half
    const int fm   = lane & 15;
    const int fq   = lane >> 4;

    const int bm0 = blockIdx.x * 128 + m4 * 64;   // wave's M base
    const int bn0 = blockIdx.y * 128;             // block's N base

    // x staging: lane owns row (bm0 + lane)
    const float* xrow = x + (size_t)(bm0 + lane) * I_DIM;
    float* xslot = &smem[wave * 1024];            // [buf(512)][lane*8]

    f32x4 acc[4][8];
#pragma unroll
    for (int a = 0; a < 4; ++a)
#pragma unroll
        for (int b = 0; b < 8; ++b)
            acc[a][b] = (f32x4){0.0f, 0.0f, 0.0f, 0.0f};

    for (int it = 0; it < KH_ITERS; ++it) {
        const int g8  = (kh * KH_ITERS + it) * 8;   // this iter's i base
        const int buf = (it & 1) * 512;

        // ---- x load: 32B of own row (2 x dwordx4) ----
        const float4 xa = *reinterpret_cast<const float4*>(xrow + g8);
        const float4 xb = *reinterpret_cast<const float4*>(xrow + g8 + 4);

        // ---- B frags: direct from global (L2-resident W), 16B each ----
        s8v bfr0[8], bfr1[8];
        if (PRECONV) {
            const u16* wb0 = wbf + ((size_t)(g8 + fq) * O_DIM + bn0 + fm) * NDEG;
            const u16* wb1 = wb0 + (size_t)4 * O_DIM * NDEG;   // i += 4
#pragma unroll
            for (int tn = 0; tn < 8; ++tn)
                bfr0[tn] = *reinterpret_cast<const s8v*>(wb0 + tn * 16 * NDEG);
#pragma unroll
            for (int tn = 0; tn < 8; ++tn)
                bfr1[tn] = *reinterpret_cast<const s8v*>(wb1 + tn * 16 * NDEG);
        } else {
            const float* wb0 = cf + ((size_t)(g8 + fq) * O_DIM + bn0 + fm) * NDEG;
            const float* wb1 = wb0 + (size_t)4 * O_DIM * NDEG;
#pragma unroll
            for (int tn = 0; tn < 8; ++tn) {
                const float4 w0 = reinterpret_cast<const float4*>(wb0 + tn * 16 * NDEG)[0];
                const float4 w1 = reinterpret_cast<const float4*>(wb0 + tn * 16 * NDEG)[1];
                union { s8v s; unsigned u[4]; } pk;
                pk.u[0] = cvt_pk_bf16(w0.x, w0.y);
                pk.u[1] = cvt_pk_bf16(w0.z, w0.w);
                pk.u[2] = cvt_pk_bf16(w1.x, w1.y);
                pk.u[3] = cvt_pk_bf16(w1.z, w1.w);
                bfr0[tn] = pk.s;
            }
#pragma unroll
            for (int tn = 0; tn < 8; ++tn) {
                const float4 w0 = reinterpret_cast<const float4*>(wb1 + tn * 16 * NDEG)[0];
                const float4 w1 = reinterpret_cast<const float4*>(wb1 + tn * 16 * NDEG)[1];
                union { s8v s; unsigned u[4]; } pk;
                pk.u[0] = cvt_pk_bf16(w0.x, w0.y);
                pk.u[1] = cvt_pk_bf16(w0.z, w0.w);
                pk.u[2] = cvt_pk_bf16(w1.x, w1.y);
                pk.u[3] = cvt_pk_bf16(w1.z, w1.w);
                bfr1[tn] = pk.s;
            }
        }

        // ---- restage x through private LDS slot (wave-synchronous) ----
        *reinterpret_cast<f32x4*>(&xslot[buf + lane * 8])     = (f32x4){xa.x, xa.y, xa.z, xa.w};
        *reinterpret_cast<f32x4*>(&xslot[buf + lane * 8 + 4]) = (f32x4){xb.x, xb.y, xb.z, xb.w};
        asm volatile("s_waitcnt lgkmcnt(0)" ::: "memory");   // wave-level: all 64 lanes' writes visible
        __builtin_amdgcn_sched_barrier(0);

        // ---- read the 8 scalars this lane needs; features in registers ----
        s8v afr0[4], afr1[4];
#pragma unroll
        for (int tm = 0; tm < 4; ++tm) {
            const float xv0 = xslot[buf + (tm * 16 + fm) * 8 + fq];        // kc=0: i = g8+fq
            const float xv1 = xslot[buf + (tm * 16 + fm) * 8 + 4 + fq];    // kc=1: i = g8+4+fq
            afr0[tm] = feat_frag(xv0);
            afr1[tm] = feat_frag(xv1);
        }

        // ---- 64 MFMAs ----
#pragma unroll
        for (int tm = 0; tm < 4; ++tm)
#pragma unroll
            for (int tn = 0; tn < 8; ++tn)
                acc[tm][tn] = __builtin_amdgcn_mfma_f32_16x16x32_bf16(
                    afr0[tm], bfr0[tn], acc[tm][tn], 0, 0, 0);
#pragma unroll
        for (int tm = 0; tm < 4; ++tm)
#pragma unroll
            for (int tn = 0; tn < 8; ++tn)
                acc[tm][tn] = __builtin_amdgcn_mfma_f32_16x16x32_bf16(
                    afr1[tm], bfr1[tn], acc[tm][tn], 0, 0, 0);
    }

    // ---- epilogue: K-half pair-reduction via LDS, chunked by tm ----
    // C/D frag: col=fm, row=fq*4+r within 16x16 tile (tm*16, tn*16).
    __syncthreads();   // xs slots done; smem becomes reduce buffer
#pragma unroll
    for (int tm = 0; tm < 4; ++tm) {
        if (kh == 1) {
#pragma unroll
            for (int tn = 0; tn < 8; ++tn)
#pragma unroll
                for (int r = 0; r < 4; ++r)
                    smem[m4 * 2048 + (fq * 4 + r) * 128 + tn * 16 + fm] = acc[tm][tn][r];
        }
        __syncthreads();
        if (kh == 0) {
#pragma unroll
            for (int tn = 0; tn < 8; ++tn) {
                const int row = bm0 + tm * 16 + fq * 4;
                const int col = bn0 + tn * 16 + fm;
#pragma unroll
                for (int r = 0; r < 4; ++r)
                    out[(size_t)(row + r) * O_DIM + col] =
                        acc[tm][tn][r] + smem[m4 * 2048 + (fq * 4 + r) * 128 + tn * 16 + fm];
            }
        }
        __syncthreads();
    }
}

extern "C" void kernel_launch(void* const* d_in, const int* in_sizes, int n_in,
                              void* d_out, int out_size, void* d_ws, size_t ws_size,
                              hipStream_t stream) {
    const float* x  = (const float*)d_in[0];
    const float* cf = (const float*)d_in[1];
    float* out = (float*)d_out;
    const int M = in_sizes[0] / I_DIM;            // 16384
    dim3 grid(M / 128, O_DIM / 128);              // (128, 4) = 512 blocks = 2/CU
    dim3 block(256, 1, 1);

    if (ws_size >= (size_t)W_ELEMS * sizeof(u16)) {
        u16* wbf = (u16*)d_ws;
        cvt_w<<<W_ELEMS / 1024, 256, 0, stream>>>(cf, wbf);
        gegen_gemm<true><<<grid, block, 0, stream>>>(x, cf, wbf, out);
    } else {
        gegen_gemm<false><<<grid, block, 0, stream>>>(x, cf, nullptr, out);
    }
}